// Round 1
// baseline (106.545 us; speedup 1.0000x reference)
//
#include <hip/hip_runtime.h>
#include <hip/hip_bf16.h>

// B=8, N=256, D=128, H=256, K=128
// out[b,i,j,k] = exp(-(v - means[k])^2 * |temps[k]|)
//   v    = mul * x[b,i,j] + bias
//   mul  = (sum_h relu(hi[b,i,h]+hj[b,j,h]+b1[h]) * W2[h,0] + b2[0]) * 0.0625
//   bias = (                 "                    * W2[h,1] + b2[1]) * 0.0625
//   hi = atom @ W1[:128], hj = atom @ W1[128:]

#define NB 8
#define NN 256
#define ND 128
#define NH 256
#define NK 128

// ---------------- Kernel A: hi / hjb = hj + b1 precompute ----------------
// grid 256 blocks, 256 threads; each block does 8 (b,n) rows.
__global__ __launch_bounds__(256) void precompute_hij(
    const float* __restrict__ atom, const float* __restrict__ W1,
    const float* __restrict__ b1,
    float* __restrict__ hi, float* __restrict__ hjb) {
  const int h = threadIdx.x;          // 0..255
  const int base = blockIdx.x * 8;    // bn base
  __shared__ float a[8][ND];
  for (int t = threadIdx.x; t < 8 * ND; t += 256) {
    a[t >> 7][t & 127] = atom[(size_t)base * ND + t];
  }
  __syncthreads();
  float acc0[8], acc1[8];
  const float bv = b1[h];
#pragma unroll
  for (int r = 0; r < 8; ++r) { acc0[r] = 0.f; acc1[r] = bv; }
  for (int d = 0; d < ND; ++d) {
    const float w0 = W1[d * NH + h];
    const float w1 = W1[(ND + d) * NH + h];
#pragma unroll
    for (int r = 0; r < 8; ++r) {
      acc0[r] = fmaf(a[r][d], w0, acc0[r]);
      acc1[r] = fmaf(a[r][d], w1, acc1[r]);
    }
  }
#pragma unroll
  for (int r = 0; r < 8; ++r) {
    hi[(size_t)(base + r) * NH + h]  = acc0[r];
    hjb[(size_t)(base + r) * NH + h] = acc1[r];
  }
}

// ---------------- Kernel B: per-edge dot + RBF ----------------
// grid = B*N blocks (one per (b,i) row), 256 threads = 4 waves.
// Each wave handles one j at a time (j = wave + 4*iter).
// Lane l owns h = 4l..4l+3; k = 2l, 2l+1.
__global__ __launch_bounds__(256) void edge_rbf(
    const float* __restrict__ x,
    const float* __restrict__ hi, const float* __restrict__ hjb,
    const float* __restrict__ W2, const float* __restrict__ b2,
    const float* __restrict__ means, const float* __restrict__ temps,
    float* __restrict__ out) {
  const int bi   = blockIdx.x;        // b*N + i
  const int b    = bi >> 8;
  const int lane = threadIdx.x & 63;
  const int wave = threadIdx.x >> 6;  // 0..3

  // hoisted per-lane state
  const float4 hiv = *reinterpret_cast<const float4*>(hi + (size_t)bi * NH + lane * 4);
  float w20[4], w21[4];
#pragma unroll
  for (int q = 0; q < 4; ++q) {
    w20[q] = W2[(lane * 4 + q) * 2 + 0];
    w21[q] = W2[(lane * 4 + q) * 2 + 1];
  }
  const float m0 = means[2 * lane];
  const float m1 = means[2 * lane + 1];
  const float LOG2E = 1.44269504088896340736f;
  const float t0 = fabsf(temps[2 * lane])     * LOG2E;
  const float t1 = fabsf(temps[2 * lane + 1]) * LOG2E;
  const float b20 = b2[0];
  const float b21 = b2[1];
  const float scale = 0.0625f;  // 1/sqrt(2*128)

  const float* __restrict__ hjbase = hjb + (size_t)b * NN * NH;
  const float* __restrict__ xrow   = x + (size_t)bi * NN;
  float* __restrict__ orow         = out + (size_t)bi * NN * NK;

  for (int j = wave; j < NN; j += 4) {
    const float4 hjv = *reinterpret_cast<const float4*>(hjbase + (size_t)j * NH + lane * 4);
    const float xv = xrow[j];

    const float h0 = fmaxf(hiv.x + hjv.x, 0.f);
    const float h1 = fmaxf(hiv.y + hjv.y, 0.f);
    const float h2 = fmaxf(hiv.z + hjv.z, 0.f);
    const float h3 = fmaxf(hiv.w + hjv.w, 0.f);

    float s0 = fmaf(h3, w20[3], fmaf(h2, w20[2], fmaf(h1, w20[1], h0 * w20[0])));
    float s1 = fmaf(h3, w21[3], fmaf(h2, w21[2], fmaf(h1, w21[1], h0 * w21[0])));

#pragma unroll
    for (int off = 32; off > 0; off >>= 1) {
      s0 += __shfl_xor(s0, off, 64);
      s1 += __shfl_xor(s1, off, 64);
    }

    const float mul  = (s0 + b20) * scale;
    const float bias = (s1 + b21) * scale;
    const float v = fmaf(mul, xv, bias);

    const float d0 = v - m0;
    const float d1 = v - m1;
    const float e0 = __builtin_amdgcn_exp2f(-(d0 * d0) * t0);
    const float e1 = __builtin_amdgcn_exp2f(-(d1 * d1) * t1);

    reinterpret_cast<float2*>(orow + (size_t)j * NK)[lane] = make_float2(e0, e1);
  }
}

extern "C" void kernel_launch(void* const* d_in, const int* in_sizes, int n_in,
                              void* d_out, int out_size, void* d_ws, size_t ws_size,
                              hipStream_t stream) {
  const float* x     = (const float*)d_in[0];
  const float* atom  = (const float*)d_in[1];
  const float* W1    = (const float*)d_in[2];
  const float* b1    = (const float*)d_in[3];
  const float* W2    = (const float*)d_in[4];
  const float* b2    = (const float*)d_in[5];
  const float* means = (const float*)d_in[6];
  const float* temps = (const float*)d_in[7];
  float* out = (float*)d_out;

  float* hi  = (float*)d_ws;                         // 2 MB
  float* hjb = hi + (size_t)NB * NN * NH;            // 2 MB

  precompute_hij<<<NB * NN / 8, 256, 0, stream>>>(atom, W1, b1, hi, hjb);
  edge_rbf<<<NB * NN, 256, 0, stream>>>(x, hi, hjb, W2, b2, means, temps, out);
}

// Round 2
// 80.055 us; speedup vs baseline: 1.3309x; 1.3309x over previous
//
#include <hip/hip_runtime.h>
#include <hip/hip_bf16.h>

// B=8, N=256, D=128, H=256, K=128
// out[b,i,j,k] = exp(-(v - means[k])^2 * |temps[k]|)
//   v    = mul * x[b,i,j] + bias
//   mul  = (sum_h relu(hi[b,i,h]+hj[b,j,h]+b1[h]) * W2[h,0] + b2[0]) * 0.0625
//   bias = (                 "                    * W2[h,1] + b2[1]) * 0.0625

#define NB 8
#define NN 256
#define ND 128
#define NH 256
#define NK 128

// ---------------- Kernel A: hi[bi][h] and hjbT[b][h][j] = hj + b1 ----------------
// grid 256 blocks, 256 threads; each block does 8 consecutive (b,n) rows (same b).
__global__ __launch_bounds__(256) void precompute_hij(
    const float* __restrict__ atom, const float* __restrict__ W1,
    const float* __restrict__ b1,
    float* __restrict__ hi, float* __restrict__ hjbT) {
  const int h = threadIdx.x;          // 0..255
  const int base = blockIdx.x * 8;    // bn base (multiple of 8 -> same b)
  const int b  = base >> 8;
  const int j0 = base & 255;
  __shared__ float a[8][ND];
  for (int t = threadIdx.x; t < 8 * ND; t += 256) {
    a[t >> 7][t & 127] = atom[(size_t)base * ND + t];
  }
  __syncthreads();
  float acc0[8], acc1[8];
  const float bv = b1[h];
#pragma unroll
  for (int r = 0; r < 8; ++r) { acc0[r] = 0.f; acc1[r] = bv; }
  for (int d = 0; d < ND; ++d) {
    const float w0 = W1[d * NH + h];
    const float w1 = W1[(ND + d) * NH + h];
#pragma unroll
    for (int r = 0; r < 8; ++r) {
      acc0[r] = fmaf(a[r][d], w0, acc0[r]);
      acc1[r] = fmaf(a[r][d], w1, acc1[r]);
    }
  }
#pragma unroll
  for (int r = 0; r < 8; ++r) {
    hi[(size_t)(base + r) * NH + h] = acc0[r];
    hjbT[((size_t)b * NH + h) * NN + (j0 + r)] = acc1[r];
  }
}

// ---------------- Kernel B: per-row edge dot + RBF ----------------
// grid = B*N blocks (one per (b,i)); b = blockIdx&7 for XCD-L2 locality.
// 256 threads = 4 waves.
// Phase 1: wave w reduces h in [64w,64w+64); lane l accumulates j=4l..4l+3.
// Phase 2: lane l covers k=4(l&31)..+3 for 2 j-rows per iter.
__global__ __launch_bounds__(256) void edge_rbf(
    const float* __restrict__ x,
    const float* __restrict__ hi, const float* __restrict__ hjbT,
    const float* __restrict__ W2, const float* __restrict__ b2,
    const float* __restrict__ means, const float* __restrict__ temps,
    float* __restrict__ out) {
  const int b    = blockIdx.x & 7;       // XCD swizzle: blockIdx%8 -> same XCD
  const int i    = blockIdx.x >> 3;
  const int bi   = b * NN + i;
  const int lane = threadIdx.x & 63;
  const int wave = threadIdx.x >> 6;     // 0..3

  __shared__ float part0[4][NN];
  __shared__ float part1[4][NN];
  __shared__ float vsh[NN];

  // ---- Phase 1: partial dot over h in [64w, 64w+64), lanes over j ----
  const float* __restrict__ hjrow = hjbT + ((size_t)b * NH + wave * 64) * NN;
  const float* __restrict__ hirow = hi + (size_t)bi * NH + wave * 64;
  const float* __restrict__ w2row = W2 + wave * 128;

  float acc0[4] = {0.f, 0.f, 0.f, 0.f};
  float acc1[4] = {0.f, 0.f, 0.f, 0.f};
#pragma unroll 8
  for (int hh = 0; hh < 64; ++hh) {
    const float4 hj4 = *reinterpret_cast<const float4*>(hjrow + (size_t)hh * NN + 4 * lane);
    const float hih = hirow[hh];        // wave-uniform -> s_load
    const float w0  = w2row[2 * hh];    // wave-uniform
    const float w1  = w2row[2 * hh + 1];
    float a0 = fmaxf(hih + hj4.x, 0.f);
    float a1 = fmaxf(hih + hj4.y, 0.f);
    float a2 = fmaxf(hih + hj4.z, 0.f);
    float a3 = fmaxf(hih + hj4.w, 0.f);
    acc0[0] = fmaf(a0, w0, acc0[0]); acc1[0] = fmaf(a0, w1, acc1[0]);
    acc0[1] = fmaf(a1, w0, acc0[1]); acc1[1] = fmaf(a1, w1, acc1[1]);
    acc0[2] = fmaf(a2, w0, acc0[2]); acc1[2] = fmaf(a2, w1, acc1[2]);
    acc0[3] = fmaf(a3, w0, acc0[3]); acc1[3] = fmaf(a3, w1, acc1[3]);
  }
  *reinterpret_cast<float4*>(&part0[wave][4 * lane]) = make_float4(acc0[0], acc0[1], acc0[2], acc0[3]);
  *reinterpret_cast<float4*>(&part1[wave][4 * lane]) = make_float4(acc1[0], acc1[1], acc1[2], acc1[3]);
  __syncthreads();

  // ---- Reduce across waves + v = mul*x + bias (thread t = j) ----
  {
    const int t = threadIdx.x;
    const float s0 = part0[0][t] + part0[1][t] + part0[2][t] + part0[3][t];
    const float s1 = part1[0][t] + part1[1][t] + part1[2][t] + part1[3][t];
    const float scale = 0.0625f;  // 1/sqrt(2*128)
    const float mul  = (s0 + b2[0]) * scale;
    const float bias = (s1 + b2[1]) * scale;
    vsh[t] = fmaf(mul, x[(size_t)bi * NN + t], bias);
  }
  __syncthreads();

  // ---- Phase 2: RBF + store. wave w covers j in [64w, 64w+64), 2 j per iter ----
  const int k0 = (lane & 31) * 4;
  const float LOG2E = 1.44269504088896340736f;
  const float4 mv = *reinterpret_cast<const float4*>(means + k0);
  float4 tv = *reinterpret_cast<const float4*>(temps + k0);
  tv.x = -fabsf(tv.x) * LOG2E;
  tv.y = -fabsf(tv.y) * LOG2E;
  tv.z = -fabsf(tv.z) * LOG2E;
  tv.w = -fabsf(tv.w) * LOG2E;

  float* __restrict__ orow = out + ((size_t)bi * NN + wave * 64) * NK;
  const int jhalf = lane >> 5;  // 0 or 1
#pragma unroll 4
  for (int c = 0; c < 32; ++c) {
    const int j = 2 * c + jhalf;
    const float vj = vsh[wave * 64 + j];
    const float d0 = vj - mv.x;
    const float d1 = vj - mv.y;
    const float d2 = vj - mv.z;
    const float d3 = vj - mv.w;
    float4 e;
    e.x = __builtin_amdgcn_exp2f(d0 * d0 * tv.x);
    e.y = __builtin_amdgcn_exp2f(d1 * d1 * tv.y);
    e.z = __builtin_amdgcn_exp2f(d2 * d2 * tv.z);
    e.w = __builtin_amdgcn_exp2f(d3 * d3 * tv.w);
    *reinterpret_cast<float4*>(orow + (size_t)j * NK + k0) = e;
  }
}

extern "C" void kernel_launch(void* const* d_in, const int* in_sizes, int n_in,
                              void* d_out, int out_size, void* d_ws, size_t ws_size,
                              hipStream_t stream) {
  const float* x     = (const float*)d_in[0];
  const float* atom  = (const float*)d_in[1];
  const float* W1    = (const float*)d_in[2];
  const float* b1    = (const float*)d_in[3];
  const float* W2    = (const float*)d_in[4];
  const float* b2    = (const float*)d_in[5];
  const float* means = (const float*)d_in[6];
  const float* temps = (const float*)d_in[7];
  float* out = (float*)d_out;

  float* hi   = (float*)d_ws;                        // 2 MB: [B*N][H]
  float* hjbT = hi + (size_t)NB * NN * NH;           // 2 MB: [B][H][N]

  precompute_hij<<<NB * NN / 8, 256, 0, stream>>>(atom, W1, b1, hi, hjbT);
  edge_rbf<<<NB * NN, 256, 0, stream>>>(x, hi, hjbT, W2, b2, means, temps, out);
}